// Round 9
// baseline (181.187 us; speedup 1.0000x reference)
//
#include <hip/hip_runtime.h>

#define D_  256
#define H1_ 256
#define H2_ 128
#define B_  2
#define LQ_ 512
#define LK_ 512
#define BK  64

typedef float  f32x4  __attribute__((ext_vector_type(4)));
typedef __bf16 bf16x8 __attribute__((ext_vector_type(8)));
typedef __bf16 bf16x4 __attribute__((ext_vector_type(4)));

// ---- prep: qp/kp projections + W2 in fragment-linear bf16 (R6-proven) ----
__global__ __launch_bounds__(512) void prep_kernel(
    const float* __restrict__ query, const float* __restrict__ key,
    const float* __restrict__ W1, const float* __restrict__ b1,
    const float* __restrict__ W2,
    float* __restrict__ qp, float* __restrict__ kp, __bf16* __restrict__ w2f) {
  const int blk = blockIdx.x;
  const int tid = threadIdx.x;
  if (blk >= 512) {
    const int id   = (blk - 512) * 512 + tid;   // 0..32767
    const int j    = id & 7;
    const int lane = (id >> 3) & 63;
    const int frag = id >> 9;                   // 0..63
    const int nt = frag & 3;
    const int wn = (frag >> 2) & 1;
    const int ks = (frag >> 3) & 1;
    const int kc = frag >> 4;
    const int n = wn * 64 + nt * 16 + (lane & 15);
    const int k = kc * 64 + ks * 32 + ((lane >> 4) << 3) + j;
    w2f[id] = (__bf16)W2[k * H2_ + n];
    return;
  }
  __shared__ float in_lds[4][D_];
  __shared__ float part[4][H1_];
  const int row0 = blk * 4;
  const int sel  = row0 >> 10;
  const float* __restrict__ src = sel ? key : query;
  const int base = (row0 & 1023) * D_;
  for (int i = tid; i < 4 * D_; i += 512)
    in_lds[i >> 8][i & 255] = src[base + i];
  __syncthreads();
  const int h  = tid & 255;
  const int kh = tid >> 8;
  float acc[4] = {0.f, 0.f, 0.f, 0.f};
  const float* __restrict__ w = W1 + sel * D_ * H1_ + kh * 128 * H1_ + h;
#pragma unroll 4
  for (int dd = 0; dd < 128; ++dd) {
    const float wv = w[dd * H1_];
    const int d = kh * 128 + dd;
#pragma unroll
    for (int r = 0; r < 4; ++r) acc[r] += in_lds[r][d] * wv;
  }
  if (kh == 1) {
#pragma unroll
    for (int r = 0; r < 4; ++r) part[r][h] = acc[r];
  }
  __syncthreads();
  if (kh == 0) {
    const float bias = sel ? 0.0f : b1[h];
    float* __restrict__ dst = sel ? kp : qp;
#pragma unroll
    for (int r = 0; r < 4; ++r)
      dst[base + r * H1_ + h] = acc[r] + part[r][h] + bias;
  }
}

// ---- score v6: M=128 tile, 256 thr / 4 waves. DIRECT-REGISTER A formation:
// A-frag lane mapping (m=lane&15, k=quad*8+j) means qi=wm*4+mt (lane-uniform)
// and ki=l16 — each lane forms its own fragment from qp/kp loads. No LDS
// staging, no K-loop barriers. B-frags from w2f (frag-linear, L2-hit).
__global__ __launch_bounds__(256) void score_kernel(
    const float* __restrict__ qp, const float* __restrict__ kp,
    const __bf16* __restrict__ w2f,
    const float* __restrict__ b2, const float* __restrict__ W3,
    const float* __restrict__ b3, float* __restrict__ scores) {
  __shared__ float spart[2][128];   // epilogue only (1 KB)

  const int b  = blockIdx.z;
  const int q0 = blockIdx.y * 8;
  const int k0 = blockIdx.x * 16;
  const int tid  = threadIdx.x;
  const int wave = tid >> 6;
  const int lane = tid & 63;
  const int quad = lane >> 4;
  const int l16  = lane & 15;
  const int wm   = wave >> 1;
  const int wn   = wave & 1;

  const float* __restrict__ qpb = qp + (b * LQ_ + q0) * H1_;
  const float* __restrict__ kpb = kp + (b * LK_ + k0) * H1_;
  // per-lane base pointers; all K-loop loads become immediate offsets (<4 KB)
  const float* __restrict__ krow = kpb + l16 * H1_ + quad * 8;
  const float* __restrict__ qrow = qpb + (wm * 4) * H1_ + quad * 8;
  const __bf16* __restrict__ wb  = w2f + (wn * 4 * 64 + lane) * 8;

  f32x4 acc[4][4];
#pragma unroll
  for (int mt = 0; mt < 4; ++mt)
#pragma unroll
    for (int nt = 0; nt < 4; ++nt)
      acc[mt][nt] = (f32x4){0.f, 0.f, 0.f, 0.f};

#pragma unroll
  for (int kc = 0; kc < 4; ++kc) {
#pragma unroll
    for (int ks = 0; ks < 2; ++ks) {
      const int ko = kc * 64 + ks * 32;
      // B fragments for this (kc,ks): 4 coalesced 16-B loads
      bf16x8 bfr[4];
#pragma unroll
      for (int nt = 0; nt < 4; ++nt)
        bfr[nt] = *(const bf16x8*)(wb + ((kc * 2 + ks) * 8 + nt) * 512);
      // A fragments: kv row shared across mt; qv row lane-uniform per mt
      const float4 kv0 = *(const float4*)(krow + ko);
      const float4 kv1 = *(const float4*)(krow + ko + 4);
      bf16x8 af[4];
#pragma unroll
      for (int mt = 0; mt < 4; ++mt) {
        const float4 qv0 = *(const float4*)(qrow + mt * H1_ + ko);
        const float4 qv1 = *(const float4*)(qrow + mt * H1_ + ko + 4);
        af[mt][0] = (__bf16)fmaxf(qv0.x + kv0.x, 0.f);
        af[mt][1] = (__bf16)fmaxf(qv0.y + kv0.y, 0.f);
        af[mt][2] = (__bf16)fmaxf(qv0.z + kv0.z, 0.f);
        af[mt][3] = (__bf16)fmaxf(qv0.w + kv0.w, 0.f);
        af[mt][4] = (__bf16)fmaxf(qv1.x + kv1.x, 0.f);
        af[mt][5] = (__bf16)fmaxf(qv1.y + kv1.y, 0.f);
        af[mt][6] = (__bf16)fmaxf(qv1.z + kv1.z, 0.f);
        af[mt][7] = (__bf16)fmaxf(qv1.w + kv1.w, 0.f);
      }
#pragma unroll
      for (int mt = 0; mt < 4; ++mt)
#pragma unroll
        for (int nt = 0; nt < 4; ++nt)
          acc[mt][nt] = __builtin_amdgcn_mfma_f32_16x16x32_bf16(
              af[mt], bfr[nt], acc[mt][nt], 0, 0, 0);
    }
  }

  // --- epilogue: score = sum_n relu(h2 + b2[n]) * W3[n] + b3 (proven) ---
  float part[4][4];
#pragma unroll
  for (int mt = 0; mt < 4; ++mt)
#pragma unroll
    for (int rg = 0; rg < 4; ++rg) part[mt][rg] = 0.f;
#pragma unroll
  for (int nt = 0; nt < 4; ++nt) {
    const int col = wn * 64 + nt * 16 + l16;
    const float b2v = b2[col];
    const float w3v = W3[col];
#pragma unroll
    for (int mt = 0; mt < 4; ++mt)
#pragma unroll
      for (int rg = 0; rg < 4; ++rg) {
        float h2 = acc[mt][nt][rg] + b2v;
        h2 = fmaxf(h2, 0.f);
        part[mt][rg] += h2 * w3v;
      }
  }
#pragma unroll
  for (int off = 1; off < 16; off <<= 1)
#pragma unroll
    for (int mt = 0; mt < 4; ++mt)
#pragma unroll
      for (int rg = 0; rg < 4; ++rg)
        part[mt][rg] += __shfl_xor(part[mt][rg], off, 64);
  if (l16 == 0) {
#pragma unroll
    for (int mt = 0; mt < 4; ++mt)
#pragma unroll
      for (int rg = 0; rg < 4; ++rg) {
        const int rl = wm * 64 + mt * 16 + quad * 4 + rg;
        spart[wn][rl] = part[mt][rg];
      }
  }
  __syncthreads();
  if (tid < 128) {
    const float s = spart[0][tid] + spart[1][tid] + b3[0];
    const int qi2 = tid >> 4, ki2 = tid & 15;
    scores[(b * LQ_ + q0 + qi2) * LK_ + k0 + ki2] = s;
  }
}

// ---- smout v2 (R7): 512 blocks x 512 thr; 4 q-rows, d-half per block.
// Probs stored transposed a_lds[k][q] -> phase-2 reads one b128 per k.
__global__ __launch_bounds__(512) void smout_kernel(
    const float* __restrict__ sc, float* __restrict__ attn,
    const int* __restrict__ mask, const float* __restrict__ value,
    float* __restrict__ out) {
  const int ds = blockIdx.x, qg = blockIdx.y, b = blockIdx.z;
  const int tid = threadIdx.x;
  __shared__ __align__(16) float a_lds[LK_][4];   // 8 KB, [k][q]
  __shared__ float p_lds[3][4][128];              // 6 KB
  const int row0 = b * LQ_ + qg * 4;
  const int w = tid >> 6, lane = tid & 63;
  if (w < 4) {
    const float* __restrict__ srow = sc + (row0 + w) * LK_;
    const int*  __restrict__ mrow = mask + (row0 + w) * LK_;
    float v[8];
#pragma unroll
    for (int j = 0; j < 8; ++j) {
      float s = srow[lane + j * 64];
      if (mrow[lane + j * 64] == 0) s = -1e9f;
      v[j] = s;
    }
    float m = v[0];
#pragma unroll
    for (int j = 1; j < 8; ++j) m = fmaxf(m, v[j]);
#pragma unroll
    for (int off = 32; off; off >>= 1) m = fmaxf(m, __shfl_xor(m, off, 64));
    float sum = 0.f;
#pragma unroll
    for (int j = 0; j < 8; ++j) { v[j] = __expf(v[j] - m); sum += v[j]; }
#pragma unroll
    for (int off = 32; off; off >>= 1) sum += __shfl_xor(sum, off, 64);
    const float inv = 1.f / sum;
    float* __restrict__ arow = attn + (row0 + w) * LK_;
#pragma unroll
    for (int j = 0; j < 8; ++j) {
      const float p = v[j] * inv;
      a_lds[lane + j * 64][w] = p;
      if (ds == 0) arow[lane + j * 64] = p;
    }
  }
  __syncthreads();
  const int dl = tid & 127;
  const int d  = dl + ds * 128;
  const int kh = tid >> 7;              // 0..3
  float acc[4] = {0.f, 0.f, 0.f, 0.f};
  const float* __restrict__ vb = value + (b * LK_ + kh * 128) * D_ + d;
#pragma unroll 4
  for (int k = 0; k < 128; ++k) {
    const float v = vb[k * D_];
    const f32x4 pv = *(const f32x4*)(&a_lds[kh * 128 + k][0]);
#pragma unroll
    for (int q = 0; q < 4; ++q) acc[q] += pv[q] * v;
  }
  if (kh > 0) {
#pragma unroll
    for (int q = 0; q < 4; ++q) p_lds[kh - 1][q][dl] = acc[q];
  }
  __syncthreads();
  if (kh == 0) {
    float* __restrict__ ob = out + row0 * D_ + d;
#pragma unroll
    for (int q = 0; q < 4; ++q)
      ob[q * D_] = acc[q] + p_lds[0][q][dl] + p_lds[1][q][dl] + p_lds[2][q][dl];
  }
}

extern "C" void kernel_launch(void* const* d_in, const int* in_sizes, int n_in,
                              void* d_out, int out_size, void* d_ws, size_t ws_size,
                              hipStream_t stream) {
  (void)in_sizes; (void)n_in; (void)out_size; (void)ws_size;
  const float* query = (const float*)d_in[0];
  const float* key   = (const float*)d_in[1];
  const float* value = (const float*)d_in[2];
  const int*   mask  = (const int*)d_in[3];
  const float* W1    = (const float*)d_in[4];
  const float* b1    = (const float*)d_in[5];
  const float* W2    = (const float*)d_in[6];
  const float* b2    = (const float*)d_in[7];
  const float* W3    = (const float*)d_in[8];
  const float* b3    = (const float*)d_in[9];

  float* out  = (float*)d_out;                 // (B,LQ,D)   = 262144 floats
  float* attn = out + B_ * LQ_ * D_;           // (B,LQ,LK)  = 524288 floats

  // ws: qp (2MB) + kp (2MB) + w2f (64KB) + sc scratch scores (2MB)
  float*  qp  = (float*)d_ws;
  float*  kp  = qp + B_ * LQ_ * H1_;
  __bf16* w2f = (__bf16*)(kp + B_ * LK_ * H1_);
  float*  sc  = (float*)(w2f + H2_ * H1_);

  prep_kernel<<<576, 512, 0, stream>>>(query, key, W1, b1, W2, qp, kp, w2f);
  dim3 gscore(LK_ / 16, LQ_ / 8, B_);
  score_kernel<<<gscore, 256, 0, stream>>>(qp, kp, w2f, b2, W3, b3, sc);
  smout_kernel<<<dim3(2, 128, B_), 512, 0, stream>>>(sc, attn, mask, value, out);
}

// Round 10
// 154.151 us; speedup vs baseline: 1.1754x; 1.1754x over previous
//
#include <hip/hip_runtime.h>

#define D_  256
#define H1_ 256
#define H2_ 128
#define B_  2
#define LQ_ 512
#define LK_ 512

typedef float  f32x4  __attribute__((ext_vector_type(4)));
typedef __bf16 bf16x8 __attribute__((ext_vector_type(8)));
typedef __bf16 bf16x4 __attribute__((ext_vector_type(4)));

// ---- prep: qp/kp projections + W2 in fragment-linear bf16 (R6-proven) ----
__global__ __launch_bounds__(512) void prep_kernel(
    const float* __restrict__ query, const float* __restrict__ key,
    const float* __restrict__ W1, const float* __restrict__ b1,
    const float* __restrict__ W2,
    float* __restrict__ qp, float* __restrict__ kp, __bf16* __restrict__ w2f) {
  const int blk = blockIdx.x;
  const int tid = threadIdx.x;
  if (blk >= 512) {
    const int id   = (blk - 512) * 512 + tid;   // 0..32767
    const int j    = id & 7;
    const int lane = (id >> 3) & 63;
    const int frag = id >> 9;                   // 0..63
    const int nt = frag & 3;
    const int wn = (frag >> 2) & 1;
    const int ks = (frag >> 3) & 1;
    const int kc = frag >> 4;
    const int n = wn * 64 + nt * 16 + (lane & 15);
    const int k = kc * 64 + ks * 32 + ((lane >> 4) << 3) + j;
    w2f[id] = (__bf16)W2[k * H2_ + n];
    return;
  }
  __shared__ float in_lds[4][D_];
  __shared__ float part[4][H1_];
  const int row0 = blk * 4;
  const int sel  = row0 >> 10;
  const float* __restrict__ src = sel ? key : query;
  const int base = (row0 & 1023) * D_;
  for (int i = tid; i < 4 * D_; i += 512)
    in_lds[i >> 8][i & 255] = src[base + i];
  __syncthreads();
  const int h  = tid & 255;
  const int kh = tid >> 8;
  float acc[4] = {0.f, 0.f, 0.f, 0.f};
  const float* __restrict__ w = W1 + sel * D_ * H1_ + kh * 128 * H1_ + h;
#pragma unroll 4
  for (int dd = 0; dd < 128; ++dd) {
    const float wv = w[dd * H1_];
    const int d = kh * 128 + dd;
#pragma unroll
    for (int r = 0; r < 4; ++r) acc[r] += in_lds[r][d] * wv;
  }
  if (kh == 1) {
#pragma unroll
    for (int r = 0; r < 4; ++r) part[r][h] = acc[r];
  }
  __syncthreads();
  if (kh == 0) {
    const float bias = sel ? 0.0f : b1[h];
    float* __restrict__ dst = sel ? kp : qp;
#pragma unroll
    for (int r = 0; r < 4; ++r)
      dst[base + r * H1_ + h] = acc[r] + part[r][h] + bias;
  }
}

// ---- score v7: full 128x256 A-tile formed in ONE pass (64 KB LDS, exactly
// the static limit; epilogue spart aliases dead A region), then a barrier-
// free MFMA phase: 8 K-steps, B-frags from w2f (R6-proven), A via swizzled
// ds_read_b128 (R4/R5/R6-proven 0-conflict formulas, base r*256+kc*64).
__global__ __launch_bounds__(256) void score_kernel(
    const float* __restrict__ qp, const float* __restrict__ kp,
    const __bf16* __restrict__ w2f,
    const float* __restrict__ b2, const float* __restrict__ W3,
    const float* __restrict__ b3, float* __restrict__ scores) {
  __shared__ __align__(16) __bf16 A_lds[128 * 256];   // 64 KB (the whole A)
  float* spart = (float*)A_lds;   // aliased after MFMA phase (A is dead)

  const int b  = blockIdx.z;
  const int q0 = blockIdx.y * 8;
  const int k0 = blockIdx.x * 16;
  const int tid  = threadIdx.x;
  const int wave = tid >> 6;
  const int lane = tid & 63;
  const int quad = lane >> 4;
  const int l16  = lane & 15;
  const int wm   = wave >> 1;
  const int wn   = wave & 1;
  const int h8   = l16 & 7;

  // formation mapping (R6-proven): thread owns (qi, t5, kg), iterates 8 ki
  const int qi = tid >> 5;           // 0..7
  const int t5 = (tid >> 4) & 1;     // ki-half
  const int kg = tid & 15;           // float4 group within a 64-col chunk

  const float* __restrict__ qpb = qp + (b * LQ_ + q0) * H1_;
  const float* __restrict__ kpb = kp + (b * LK_ + k0) * H1_;
  const __bf16* __restrict__ wb = w2f + (wn * 4 * 64 + lane) * 8;

  // --- phase 1: form ALL of A = relu(qp[qi]+kp[ki]) in bf16, swizzled ---
#pragma unroll
  for (int kc = 0; kc < 4; ++kc) {
    const float4 qv = *(const float4*)(qpb + qi * H1_ + kc * 64 + kg * 4);
#pragma unroll
    for (int ii = 0; ii < 8; ++ii) {
      const int ki = t5 * 8 + ii;
      const int r  = qi * 16 + ki;
      const float4 kv = *(const float4*)(kpb + ki * H1_ + kc * 64 + kg * 4);
      bf16x4 a;
      a[0] = (__bf16)fmaxf(qv.x + kv.x, 0.f);
      a[1] = (__bf16)fmaxf(qv.y + kv.y, 0.f);
      a[2] = (__bf16)fmaxf(qv.z + kv.z, 0.f);
      a[3] = (__bf16)fmaxf(qv.w + kv.w, 0.f);
      const int sw = (((kg >> 1) ^ (r & 7)) << 3) + ((kg & 1) << 2);
      *(bf16x4*)(&A_lds[r * 256 + kc * 64 + sw]) = a;
    }
  }
  __syncthreads();   // the ONLY staging barrier

  // --- phase 2: 8 MFMA K-steps, no barriers ---
  f32x4 acc[4][4];
#pragma unroll
  for (int mt = 0; mt < 4; ++mt)
#pragma unroll
    for (int nt = 0; nt < 4; ++nt)
      acc[mt][nt] = (f32x4){0.f, 0.f, 0.f, 0.f};

#pragma unroll
  for (int kk = 0; kk < 8; ++kk) {
    bf16x8 bfr[4];
#pragma unroll
    for (int nt = 0; nt < 4; ++nt)
      bfr[nt] = *(const bf16x8*)(wb + (kk * 8 + nt) * 512);
    const int kc = kk >> 1;
    const int cbase = (kk & 1) * 4 + quad;
    bf16x8 af[4];
#pragma unroll
    for (int mt = 0; mt < 4; ++mt) {
      const int ra = wm * 64 + mt * 16 + l16;
      af[mt] = *(const bf16x8*)(&A_lds[ra * 256 + kc * 64 + ((cbase ^ h8) << 3)]);
    }
#pragma unroll
    for (int mt = 0; mt < 4; ++mt)
#pragma unroll
      for (int nt = 0; nt < 4; ++nt)
        acc[mt][nt] = __builtin_amdgcn_mfma_f32_16x16x32_bf16(
            af[mt], bfr[nt], acc[mt][nt], 0, 0, 0);
  }

  // --- epilogue: score = sum_n relu(h2 + b2[n]) * W3[n] + b3 (proven) ---
  float part[4][4];
#pragma unroll
  for (int mt = 0; mt < 4; ++mt)
#pragma unroll
    for (int rg = 0; rg < 4; ++rg) part[mt][rg] = 0.f;
#pragma unroll
  for (int nt = 0; nt < 4; ++nt) {
    const int col = wn * 64 + nt * 16 + l16;
    const float b2v = b2[col];
    const float w3v = W3[col];
#pragma unroll
    for (int mt = 0; mt < 4; ++mt)
#pragma unroll
      for (int rg = 0; rg < 4; ++rg) {
        float h2 = acc[mt][nt][rg] + b2v;
        h2 = fmaxf(h2, 0.f);
        part[mt][rg] += h2 * w3v;
      }
  }
#pragma unroll
  for (int off = 1; off < 16; off <<= 1)
#pragma unroll
    for (int mt = 0; mt < 4; ++mt)
#pragma unroll
      for (int rg = 0; rg < 4; ++rg)
        part[mt][rg] += __shfl_xor(part[mt][rg], off, 64);
  __syncthreads();   // all A reads done; safe to alias spart onto A_lds
  if (l16 == 0) {
#pragma unroll
    for (int mt = 0; mt < 4; ++mt)
#pragma unroll
      for (int rg = 0; rg < 4; ++rg) {
        const int rl = wm * 64 + mt * 16 + quad * 4 + rg;
        spart[wn * 128 + rl] = part[mt][rg];
      }
  }
  __syncthreads();
  if (tid < 128) {
    const float s = spart[tid] + spart[128 + tid] + b3[0];
    const int qi2 = tid >> 4, ki2 = tid & 15;
    scores[(b * LQ_ + q0 + qi2) * LK_ + k0 + ki2] = s;
  }
}

// ---- smout v2 (R7-proven): 512 blocks x 512 thr; 4 q-rows, d-half each.
// Probs stored transposed a_lds[k][q] -> phase-2 reads one b128 per k.
__global__ __launch_bounds__(512) void smout_kernel(
    const float* __restrict__ sc, float* __restrict__ attn,
    const int* __restrict__ mask, const float* __restrict__ value,
    float* __restrict__ out) {
  const int ds = blockIdx.x, qg = blockIdx.y, b = blockIdx.z;
  const int tid = threadIdx.x;
  __shared__ __align__(16) float a_lds[LK_][4];   // 8 KB, [k][q]
  __shared__ float p_lds[3][4][128];              // 6 KB
  const int row0 = b * LQ_ + qg * 4;
  const int w = tid >> 6, lane = tid & 63;
  if (w < 4) {
    const float* __restrict__ srow = sc + (row0 + w) * LK_;
    const int*  __restrict__ mrow = mask + (row0 + w) * LK_;
    float v[8];
#pragma unroll
    for (int j = 0; j < 8; ++j) {
      float s = srow[lane + j * 64];
      if (mrow[lane + j * 64] == 0) s = -1e9f;
      v[j] = s;
    }
    float m = v[0];
#pragma unroll
    for (int j = 1; j < 8; ++j) m = fmaxf(m, v[j]);
#pragma unroll
    for (int off = 32; off; off >>= 1) m = fmaxf(m, __shfl_xor(m, off, 64));
    float sum = 0.f;
#pragma unroll
    for (int j = 0; j < 8; ++j) { v[j] = __expf(v[j] - m); sum += v[j]; }
#pragma unroll
    for (int off = 32; off; off >>= 1) sum += __shfl_xor(sum, off, 64);
    const float inv = 1.f / sum;
    float* __restrict__ arow = attn + (row0 + w) * LK_;
#pragma unroll
    for (int j = 0; j < 8; ++j) {
      const float p = v[j] * inv;
      a_lds[lane + j * 64][w] = p;
      if (ds == 0) arow[lane + j * 64] = p;
    }
  }
  __syncthreads();
  const int dl = tid & 127;
  const int d  = dl + ds * 128;
  const int kh = tid >> 7;              // 0..3
  float acc[4] = {0.f, 0.f, 0.f, 0.f};
  const float* __restrict__ vb = value + (b * LK_ + kh * 128) * D_ + d;
#pragma unroll 4
  for (int k = 0; k < 128; ++k) {
    const float v = vb[k * D_];
    const f32x4 pv = *(const f32x4*)(&a_lds[kh * 128 + k][0]);
#pragma unroll
    for (int q = 0; q < 4; ++q) acc[q] += pv[q] * v;
  }
  if (kh > 0) {
#pragma unroll
    for (int q = 0; q < 4; ++q) p_lds[kh - 1][q][dl] = acc[q];
  }
  __syncthreads();
  if (kh == 0) {
    float* __restrict__ ob = out + row0 * D_ + d;
#pragma unroll
    for (int q = 0; q < 4; ++q)
      ob[q * D_] = acc[q] + p_lds[0][q][dl] + p_lds[1][q][dl] + p_lds[2][q][dl];
  }
}

extern "C" void kernel_launch(void* const* d_in, const int* in_sizes, int n_in,
                              void* d_out, int out_size, void* d_ws, size_t ws_size,
                              hipStream_t stream) {
  (void)in_sizes; (void)n_in; (void)out_size; (void)ws_size;
  const float* query = (const float*)d_in[0];
  const float* key   = (const float*)d_in[1];
  const float* value = (const float*)d_in[2];
  const int*   mask  = (const int*)d_in[3];
  const float* W1    = (const float*)d_in[4];
  const float* b1    = (const float*)d_in[5];
  const float* W2    = (const float*)d_in[6];
  const float* b2    = (const float*)d_in[7];
  const float* W3    = (const float*)d_in[8];
  const float* b3    = (const float*)d_in[9];

  float* out  = (float*)d_out;                 // (B,LQ,D)   = 262144 floats
  float* attn = out + B_ * LQ_ * D_;           // (B,LQ,LK)  = 524288 floats

  // ws: qp (2MB) + kp (2MB) + w2f (64KB) + sc scratch scores (2MB)
  float*  qp  = (float*)d_ws;
  float*  kp  = qp + B_ * LQ_ * H1_;
  __bf16* w2f = (__bf16*)(kp + B_ * LK_ * H1_);
  float*  sc  = (float*)(w2f + H2_ * H1_);

  prep_kernel<<<576, 512, 0, stream>>>(query, key, W1, b1, W2, qp, kp, w2f);
  dim3 gscore(LK_ / 16, LQ_ / 8, B_);
  score_kernel<<<gscore, 256, 0, stream>>>(qp, kp, w2f, b2, W3, b3, sc);
  smout_kernel<<<dim3(2, 128, B_), 512, 0, stream>>>(sc, attn, mask, value, out);
}

// Round 11
// 141.090 us; speedup vs baseline: 1.2842x; 1.0926x over previous
//
#include <hip/hip_runtime.h>

#define D_  256
#define H1_ 256
#define H2_ 128
#define B_  2
#define LQ_ 512
#define LK_ 512
#define BK  64

typedef float  f32x4  __attribute__((ext_vector_type(4)));
typedef __bf16 bf16x8 __attribute__((ext_vector_type(8)));
typedef __bf16 bf16x4 __attribute__((ext_vector_type(4)));

// ---- prep: qp/kp projections + W2 in fragment-linear bf16 (R6-proven) ----
__global__ __launch_bounds__(512) void prep_kernel(
    const float* __restrict__ query, const float* __restrict__ key,
    const float* __restrict__ W1, const float* __restrict__ b1,
    const float* __restrict__ W2,
    float* __restrict__ qp, float* __restrict__ kp, __bf16* __restrict__ w2f) {
  const int blk = blockIdx.x;
  const int tid = threadIdx.x;
  if (blk >= 512) {
    const int id   = (blk - 512) * 512 + tid;   // 0..32767
    const int j    = id & 7;
    const int lane = (id >> 3) & 63;
    const int frag = id >> 9;                   // 0..63
    const int nt = frag & 3;
    const int wn = (frag >> 2) & 1;
    const int ks = (frag >> 3) & 1;
    const int kc = frag >> 4;
    const int n = wn * 64 + nt * 16 + (lane & 15);
    const int k = kc * 64 + ks * 32 + ((lane >> 4) << 3) + j;
    w2f[id] = (__bf16)W2[k * H2_ + n];
    return;
  }
  __shared__ float in_lds[4][D_];
  __shared__ float part[4][H1_];
  const int row0 = blk * 4;
  const int sel  = row0 >> 10;
  const float* __restrict__ src = sel ? key : query;
  const int base = (row0 & 1023) * D_;
  for (int i = tid; i < 4 * D_; i += 512)
    in_lds[i >> 8][i & 255] = src[base + i];
  __syncthreads();
  const int h  = tid & 255;
  const int kh = tid >> 8;
  float acc[4] = {0.f, 0.f, 0.f, 0.f};
  const float* __restrict__ w = W1 + sel * D_ * H1_ + kh * 128 * H1_ + h;
#pragma unroll 4
  for (int dd = 0; dd < 128; ++dd) {
    const float wv = w[dd * H1_];
    const int d = kh * 128 + dd;
#pragma unroll
    for (int r = 0; r < 4; ++r) acc[r] += in_lds[r][d] * wv;
  }
  if (kh == 1) {
#pragma unroll
    for (int r = 0; r < 4; ++r) part[r][h] = acc[r];
  }
  __syncthreads();
  if (kh == 0) {
    const float bias = sel ? 0.0f : b1[h];
    float* __restrict__ dst = sel ? kp : qp;
#pragma unroll
    for (int r = 0; r < 4; ++r)
      dst[base + r * H1_ + h] = acc[r] + part[r][h] + bias;
  }
}

// ---- score: EXACT R6 revert (56.2 µs proven): A-only LDS 16.5 KB XOR-
// swizzled 0-conflict, B-frags global->register, 2 barriers per kc. ----
__global__ __launch_bounds__(256, 2) void score_kernel(
    const float* __restrict__ qp, const float* __restrict__ kp,
    const __bf16* __restrict__ w2f,
    const float* __restrict__ b2, const float* __restrict__ W3,
    const float* __restrict__ b3, float* __restrict__ scores) {
  __shared__ __align__(16) __bf16 A_lds[128 * BK];   // 16 KB
  __shared__ float  spart[2][128];                   // 1 KB

  const int b  = blockIdx.z;
  const int q0 = blockIdx.y * 8;
  const int k0 = blockIdx.x * 16;
  const int tid  = threadIdx.x;
  const int wave = tid >> 6;
  const int lane = tid & 63;
  const int quad = lane >> 4;
  const int l16  = lane & 15;
  const int wm   = wave >> 1;
  const int wn   = wave & 1;
  const int h8   = l16 & 7;

  const int qi = tid >> 5;           // 0..7
  const int t5 = (tid >> 4) & 1;     // ki-half
  const int kg = tid & 15;           // float4 group in BK

  const float* __restrict__ qpb = qp + (b * LQ_ + q0) * H1_;
  const float* __restrict__ kpb = kp + (b * LK_ + k0) * H1_;

  f32x4 acc[4][4];
#pragma unroll
  for (int mt = 0; mt < 4; ++mt)
#pragma unroll
    for (int nt = 0; nt < 4; ++nt)
      acc[mt][nt] = (f32x4){0.f, 0.f, 0.f, 0.f};

  for (int kc = 0; kc < H1_ / BK; ++kc) {
    bf16x8 bfr[2][4];
#pragma unroll
    for (int ks = 0; ks < 2; ++ks)
#pragma unroll
      for (int nt = 0; nt < 4; ++nt)
        bfr[ks][nt] = *(const bf16x8*)(
            w2f + ((((kc * 2 + ks) * 2 + wn) * 4 + nt) * 64 + lane) * 8);

    const float4 qv = *(const float4*)(qpb + qi * H1_ + kc * BK + kg * 4);
#pragma unroll
    for (int ii = 0; ii < 8; ++ii) {
      const int ki = t5 * 8 + ii;
      const int r  = qi * 16 + ki;
      const float4 kv = *(const float4*)(kpb + ki * H1_ + kc * BK + kg * 4);
      bf16x4 a;
      a[0] = (__bf16)fmaxf(qv.x + kv.x, 0.f);
      a[1] = (__bf16)fmaxf(qv.y + kv.y, 0.f);
      a[2] = (__bf16)fmaxf(qv.z + kv.z, 0.f);
      a[3] = (__bf16)fmaxf(qv.w + kv.w, 0.f);
      const int sw = (((kg >> 1) ^ (r & 7)) << 3) + ((kg & 1) << 2);
      *(bf16x4*)(&A_lds[r * BK + sw]) = a;
    }
    __syncthreads();
#pragma unroll
    for (int ks = 0; ks < 2; ++ks) {
      const int cbase = ks * 4 + quad;
      bf16x8 af[4];
#pragma unroll
      for (int mt = 0; mt < 4; ++mt) {
        const int ra = wm * 64 + mt * 16 + l16;
        af[mt] = *(const bf16x8*)(&A_lds[ra * BK + ((cbase ^ h8) << 3)]);
      }
#pragma unroll
      for (int mt = 0; mt < 4; ++mt)
#pragma unroll
        for (int nt = 0; nt < 4; ++nt)
          acc[mt][nt] = __builtin_amdgcn_mfma_f32_16x16x32_bf16(
              af[mt], bfr[ks][nt], acc[mt][nt], 0, 0, 0);
    }
    __syncthreads();
  }

  float part[4][4];
#pragma unroll
  for (int mt = 0; mt < 4; ++mt)
#pragma unroll
    for (int rg = 0; rg < 4; ++rg) part[mt][rg] = 0.f;
#pragma unroll
  for (int nt = 0; nt < 4; ++nt) {
    const int col = wn * 64 + nt * 16 + l16;
    const float b2v = b2[col];
    const float w3v = W3[col];
#pragma unroll
    for (int mt = 0; mt < 4; ++mt)
#pragma unroll
      for (int rg = 0; rg < 4; ++rg) {
        float h2 = acc[mt][nt][rg] + b2v;
        h2 = fmaxf(h2, 0.f);
        part[mt][rg] += h2 * w3v;
      }
  }
#pragma unroll
  for (int off = 1; off < 16; off <<= 1)
#pragma unroll
    for (int mt = 0; mt < 4; ++mt)
#pragma unroll
      for (int rg = 0; rg < 4; ++rg)
        part[mt][rg] += __shfl_xor(part[mt][rg], off, 64);
  if (l16 == 0) {
#pragma unroll
    for (int mt = 0; mt < 4; ++mt)
#pragma unroll
      for (int rg = 0; rg < 4; ++rg) {
        const int rl = wm * 64 + mt * 16 + quad * 4 + rg;
        spart[wn][rl] = part[mt][rg];
      }
  }
  __syncthreads();
  if (tid < 128) {
    const float s = spart[0][tid] + spart[1][tid] + b3[0];
    const int qi2 = tid >> 4, ki2 = tid & 15;
    scores[(b * LQ_ + q0 + qi2) * LK_ + k0 + ki2] = s;
  }
}

// ---- smout v3: 256 blocks x 512 thr; block owns (b, 4 q-rows) uniquely.
// Phase 1: waves 0-3 softmax one row each (proven reduce); probs -> a_lds
// transposed [k][q] and written to attn unconditionally.
// Phase 2: thread = (kh2 0..7, dv 0..63): float4 value loads (16B coalesced,
// 16 FMA per load — 4x fewer latency events than scalar), broadcast b128
// prob reads, k-split-8 combined via f32x4 LDS partials.
__global__ __launch_bounds__(512) void smout_kernel(
    const float* __restrict__ sc, float* __restrict__ attn,
    const int* __restrict__ mask, const float* __restrict__ value,
    float* __restrict__ out) {
  const int qg = blockIdx.x, b = blockIdx.y;
  const int tid = threadIdx.x;
  __shared__ __align__(16) float a_lds[LK_][4];   // 8 KB, [k][q]
  __shared__ __align__(16) f32x4 p_lds[7][4][64]; // 28 KB partials
  const int row0 = b * LQ_ + qg * 4;
  const int w = tid >> 6, lane = tid & 63;
  if (w < 4) {
    const float* __restrict__ srow = sc + (row0 + w) * LK_;
    const int*  __restrict__ mrow = mask + (row0 + w) * LK_;
    float v[8];
#pragma unroll
    for (int j = 0; j < 8; ++j) {
      float s = srow[lane + j * 64];
      if (mrow[lane + j * 64] == 0) s = -1e9f;
      v[j] = s;
    }
    float m = v[0];
#pragma unroll
    for (int j = 1; j < 8; ++j) m = fmaxf(m, v[j]);
#pragma unroll
    for (int off = 32; off; off >>= 1) m = fmaxf(m, __shfl_xor(m, off, 64));
    float sum = 0.f;
#pragma unroll
    for (int j = 0; j < 8; ++j) { v[j] = __expf(v[j] - m); sum += v[j]; }
#pragma unroll
    for (int off = 32; off; off >>= 1) sum += __shfl_xor(sum, off, 64);
    const float inv = 1.f / sum;
    float* __restrict__ arow = attn + (row0 + w) * LK_;
#pragma unroll
    for (int j = 0; j < 8; ++j) {
      const float p = v[j] * inv;
      a_lds[lane + j * 64][w] = p;
      arow[lane + j * 64] = p;
    }
  }
  __syncthreads();
  // phase 2
  const int kh2 = tid >> 6;             // 0..7 : 64-deep k chunk
  const int dv  = tid & 63;             // float4 group over d (256 = 64x4)
  f32x4 acc[4];
#pragma unroll
  for (int q = 0; q < 4; ++q) acc[q] = (f32x4){0.f, 0.f, 0.f, 0.f};
  const f32x4* __restrict__ vb4 = (const f32x4*)value + (b * LK_ + kh2 * 64) * 64 + dv;
#pragma unroll 4
  for (int k = 0; k < 64; ++k) {
    const f32x4 v4 = vb4[k * 64];
    const f32x4 p4 = *(const f32x4*)(&a_lds[kh2 * 64 + k][0]);
#pragma unroll
    for (int q = 0; q < 4; ++q) acc[q] += p4[q] * v4;
  }
  if (kh2 > 0) {
#pragma unroll
    for (int q = 0; q < 4; ++q) p_lds[kh2 - 1][q][dv] = acc[q];
  }
  __syncthreads();
  if (kh2 == 0) {
    f32x4* __restrict__ ob4 = (f32x4*)out + row0 * 64 + dv;
#pragma unroll
    for (int q = 0; q < 4; ++q) {
      f32x4 r = acc[q];
#pragma unroll
      for (int pp = 0; pp < 7; ++pp) r += p_lds[pp][q][dv];
      ob4[q * 64] = r;
    }
  }
}

extern "C" void kernel_launch(void* const* d_in, const int* in_sizes, int n_in,
                              void* d_out, int out_size, void* d_ws, size_t ws_size,
                              hipStream_t stream) {
  (void)in_sizes; (void)n_in; (void)out_size; (void)ws_size;
  const float* query = (const float*)d_in[0];
  const float* key   = (const float*)d_in[1];
  const float* value = (const float*)d_in[2];
  const int*   mask  = (const int*)d_in[3];
  const float* W1    = (const float*)d_in[4];
  const float* b1    = (const float*)d_in[5];
  const float* W2    = (const float*)d_in[6];
  const float* b2    = (const float*)d_in[7];
  const float* W3    = (const float*)d_in[8];
  const float* b3    = (const float*)d_in[9];

  float* out  = (float*)d_out;                 // (B,LQ,D)   = 262144 floats
  float* attn = out + B_ * LQ_ * D_;           // (B,LQ,LK)  = 524288 floats

  // ws: qp (2MB) + kp (2MB) + w2f (64KB) + sc scratch scores (2MB)
  float*  qp  = (float*)d_ws;
  float*  kp  = qp + B_ * LQ_ * H1_;
  __bf16* w2f = (__bf16*)(kp + B_ * LK_ * H1_);
  float*  sc  = (float*)(w2f + H2_ * H1_);

  prep_kernel<<<576, 512, 0, stream>>>(query, key, W1, b1, W2, qp, kp, w2f);
  dim3 gscore(LK_ / 16, LQ_ / 8, B_);
  score_kernel<<<gscore, 256, 0, stream>>>(qp, kp, w2f, b2, W3, b3, sc);
  smout_kernel<<<dim3(128, B_), 512, 0, stream>>>(sc, attn, mask, value, out);
}